// Round 12
// baseline (521.628 us; speedup 1.0000x reference)
//
#include <hip/hip_runtime.h>
#include <hip/hip_bf16.h>
#include <float.h>

#define BB 8
#define NNq 8192
#define SSk 2048
#define CIN 512
#define OC 256
#define NR (BB * NNq)   // 65536 total rows (b*N+n)
#define NBX 512         // GEMM row-blocks = NR/128

typedef __attribute__((ext_vector_type(8))) short bf16x8;
typedef __attribute__((ext_vector_type(8))) unsigned short ushort8;
typedef __attribute__((ext_vector_type(4))) float f32x4;
typedef __attribute__((ext_vector_type(2))) float f32x2;

__device__ __forceinline__ unsigned short f2bf(float f) {
  union { __hip_bfloat16 h; unsigned short u; } v;
  v.h = __float2bfloat16(f);
  return v.u;
}
__device__ __forceinline__ float bf2f(unsigned short u) {
  union { unsigned int i; float f; } x; x.i = ((unsigned int)u) << 16; return x.f;
}

// packed distance for 2 queries vs 1 candidate; candidate stored as (-2qx,-2qy,-2qz,qq).
// bit-exact np order: t=((x*qx'+y*qy')+z*qz'); d=((t)+pp)+qq
__device__ __forceinline__ f32x2 pkdist(f32x2 xp, f32x2 yp, f32x2 zp, f32x2 pp2,
                                        f32x2 cxy, f32x2 czw) {
  f32x2 t, m;
  asm("v_pk_mul_f32 %0, %2, %6 op_sel:[0,0] op_sel_hi:[1,0]\n\t"
      "v_pk_mul_f32 %1, %3, %6 op_sel:[0,1] op_sel_hi:[1,1]\n\t"
      "v_pk_add_f32 %0, %0, %1\n\t"
      "v_pk_mul_f32 %1, %4, %7 op_sel:[0,0] op_sel_hi:[1,0]\n\t"
      "v_pk_add_f32 %0, %0, %1\n\t"
      "v_pk_add_f32 %0, %0, %5\n\t"
      "v_pk_add_f32 %0, %0, %7 op_sel:[0,1] op_sel_hi:[1,1]"
      : "=&v"(t), "=&v"(m)
      : "v"(xp), "v"(yp), "v"(zp), "v"(pp2), "v"(cxy), "v"(czw));
  return t;
}

// 11-instr sorted-insert; strict < keeps earlier index on ties (np-stable).
__device__ __forceinline__ void insert3(float d, int ix, float& e0, float& e1, float& e2,
                                        int& i0, int& i1, int& i2) {
  int t;
  asm("v_cmp_lt_f32 vcc, %[d], %[e2]\n\t"
      "v_cndmask_b32 %[t], %[i2], %[ix], vcc\n\t"
      "v_cmp_lt_f32 vcc, %[d], %[e1]\n\t"
      "v_cndmask_b32 %[i2], %[t], %[i1], vcc\n\t"
      "v_cndmask_b32 %[t], %[i1], %[ix], vcc\n\t"
      "v_cmp_lt_f32 vcc, %[d], %[e0]\n\t"
      "v_cndmask_b32 %[i1], %[t], %[i0], vcc\n\t"
      "v_cndmask_b32 %[i0], %[i0], %[ix], vcc\n\t"
      "v_med3_f32 %[e2], %[d], %[e1], %[e2]\n\t"
      "v_med3_f32 %[e1], %[d], %[e0], %[e1]\n\t"
      "v_min_f32 %[e0], %[e0], %[d]"
      : [e0]"+v"(e0), [e1]"+v"(e1), [e2]"+v"(e2),
        [i0]"+v"(i0), [i1]"+v"(i1), [i2]"+v"(i2), [t]"=&v"(t)
      : [d]"v"(d), [ix]"v"(ix)
      : "vcc");
}

// ================================================================ fat front kernel
// knn: 512 blocks (= 4096 waves, HALF the machine) spread at id%8==0 in [0,4096)
// so each CU steadily hosts ~2 VALU-bound knn blocks + ~2 BW-bound memory blocks.
// memory blocks: tr_p1 (8192) + tr_p2 (2048) + weight cvt (384).
__global__ __launch_bounds__(512) void k_front(const float* __restrict__ xyz1,
                                               const float* __restrict__ xyz2,
                                               const float* __restrict__ p1,
                                               const float* __restrict__ p2,
                                               const float* __restrict__ w1,
                                               const float* __restrict__ w2,
                                               int* __restrict__ idx3, float* __restrict__ w3,
                                               __hip_bfloat16* __restrict__ xb,
                                               float* __restrict__ p2t,
                                               __hip_bfloat16* __restrict__ wb1,
                                               __hip_bfloat16* __restrict__ wb2) {
  __shared__ char sm[32768];
  int id = blockIdx.x;
  int type, sub;
  if (id < 4096 && (id & 7) == 0) { type = 0; sub = id >> 3; }
  else {
    int s = (id < 4096) ? (id - (id >> 3) - 1) : (id - 512);
    if (s < 8192)       { type = 1; sub = s; }
    else if (s < 10240) { type = 2; sub = s - 8192; }
    else if (s < 10624) { type = 3; sub = s - 10240; }
    else return;
  }

  if (type == 0) {
    // ---------------- knn: 128 q (2/lane), FULL 2048 candidates, 8 waves x 256-chunk
    float4* lsh = (float4*)sm;         // 32KB candidates; merge arrays overlay after scan
    float* meP = (float*)sm;           // [8][3][128] floats (12KB)
    int*   miP = (int*)sm + 3072;      // [8][3][128] ints   (12KB)
    int qblk = sub & 63, b = sub >> 6;
    int t = threadIdx.x;
    int lane = t & 63, w = t >> 6;

    // inline candidate prep from xyz2 (np-exact ops)
#pragma unroll
    for (int j = 0; j < 4; ++j) {
      int p = t + j * 512;
      const float* s = xyz2 + ((long)b * SSk + p) * 3;
      float x = s[0], y = s[1], z = s[2];
      float qq = __fadd_rn(__fadd_rn(__fmul_rn(x, x), __fmul_rn(y, y)), __fmul_rn(z, z));
      lsh[p] = make_float4(-2.f * x, -2.f * y, -2.f * z, qq);
    }

    long baseA = (long)b * NNq + qblk * 128 + lane;
    long baseB = baseA + 64;
    float xa = xyz1[baseA * 3 + 0], ya = xyz1[baseA * 3 + 1], za = xyz1[baseA * 3 + 2];
    float xb_ = xyz1[baseB * 3 + 0], yb_ = xyz1[baseB * 3 + 1], zb_ = xyz1[baseB * 3 + 2];
    float ppa = __fadd_rn(__fadd_rn(__fmul_rn(xa, xa), __fmul_rn(ya, ya)), __fmul_rn(za, za));
    float ppb = __fadd_rn(__fadd_rn(__fmul_rn(xb_, xb_), __fmul_rn(yb_, yb_)), __fmul_rn(zb_, zb_));
    f32x2 xp = {xa, xb_}, yp = {ya, yb_}, zp = {za, zb_}, pp2 = {ppa, ppb};
    __syncthreads();

    float e0a = FLT_MAX, e1a = FLT_MAX, e2a = FLT_MAX;
    float e0b = FLT_MAX, e1b = FLT_MAX, e2b = FLT_MAX;
    int i0a = 0, i1a = 0, i2a = 0, i0b = 0, i1b = 0, i2b = 0;
    const f32x4* __restrict__ qp = (const f32x4*)(lsh + w * 256);
#pragma unroll 8
    for (int ii = 0; ii < 256; ++ii) {
      f32x4 c = qp[ii];
      f32x2 d2 = pkdist(xp, yp, zp, pp2, c.xy, c.zw);
      insert3(d2.x, ii, e0a, e1a, e2a, i0a, i1a, i2a);
      insert3(d2.y, ii, e0b, e1b, e2b, i0b, i1b, i2b);
    }
    __syncthreads();   // all waves done reading candidates; safe to overlay
    int s0 = w * 256;
    meP[(w * 3 + 0) * 128 + lane] = e0a; meP[(w * 3 + 1) * 128 + lane] = e1a; meP[(w * 3 + 2) * 128 + lane] = e2a;
    meP[(w * 3 + 0) * 128 + 64 + lane] = e0b; meP[(w * 3 + 1) * 128 + 64 + lane] = e1b; meP[(w * 3 + 2) * 128 + 64 + lane] = e2b;
    miP[(w * 3 + 0) * 128 + lane] = i0a + s0; miP[(w * 3 + 1) * 128 + lane] = i1a + s0; miP[(w * 3 + 2) * 128 + lane] = i2a + s0;
    miP[(w * 3 + 0) * 128 + 64 + lane] = i0b + s0; miP[(w * 3 + 1) * 128 + 64 + lane] = i1b + s0; miP[(w * 3 + 2) * 128 + 64 + lane] = i2b + s0;
    __syncthreads();

    if (t < 128) {
      // merge 8 chunk-triples in ascending chunk order (stable ties)
      float e0 = meP[0 * 128 + t], e1 = meP[1 * 128 + t], e2 = meP[2 * 128 + t];
      int   g0 = miP[0 * 128 + t], g1 = miP[1 * 128 + t], g2 = miP[2 * 128 + t];
      for (int ww = 1; ww < 8; ++ww) {
#pragma unroll
        for (int k = 0; k < 3; ++k) {
          float d = meP[(ww * 3 + k) * 128 + t]; int s = miP[(ww * 3 + k) * 128 + t];
          if (d < e2) {
            if (d < e1) {
              e2 = e1; g2 = g1;
              if (d < e0) { e1 = e0; g1 = g0; e0 = d; g0 = s; }
              else        { e1 = d; g1 = s; }
            } else { e2 = d; g2 = s; }
          }
        }
      }
      long base = (long)b * NNq + qblk * 128 + t;
      float r0 = 1.f / (e0 + 1e-8f), r1 = 1.f / (e1 + 1e-8f), r2 = 1.f / (e2 + 1e-8f);
      float rs = r0 + r1 + r2;
      idx3[base * 3 + 0] = g0; idx3[base * 3 + 1] = g1; idx3[base * 3 + 2] = g2;
      w3[base * 3 + 0] = r0 / rs; w3[base * 3 + 1] = r1 / rs; w3[base * 3 + 2] = r2 / rs;
    }
  } else if (type == 1) {
    // ---------------- transpose p1 [b][c][n] f32 -> xb[:,0:256] bf16 (two 32x32 tiles/block)
    int th = threadIdx.x & 255, hsub = threadIdx.x >> 8;
    float (*T)[33] = (float(*)[33])((float*)sm + hsub * (32 * 33));
    int b = sub >> 10, c0 = ((sub >> 7) & 7) * 32, n0 = (sub & 127) * 64 + hsub * 32;
    int tx = th & 31, ty = th >> 5;
#pragma unroll
    for (int r = 0; r < 32; r += 8)
      T[ty + r][tx] = p1[((long)(b * 256 + c0 + ty + r)) * NNq + n0 + tx];
    __syncthreads();
#pragma unroll
    for (int r = 0; r < 32; r += 8)
      xb[((long)(b * NNq + n0 + ty + r)) * CIN + c0 + tx] = __float2bfloat16(T[tx][ty + r]);
  } else if (type == 2) {
    // ---------------- transpose p2 [b][c][s] f32 -> p2t [b][s][256] f32
    int th = threadIdx.x & 255, hsub = threadIdx.x >> 8;
    float (*T)[33] = (float(*)[33])((float*)sm + hsub * (32 * 33));
    int b = sub >> 8, c0 = ((sub >> 5) & 7) * 32, s0 = (sub & 31) * 64 + hsub * 32;
    int tx = th & 31, ty = th >> 5;
#pragma unroll
    for (int r = 0; r < 32; r += 8)
      T[ty + r][tx] = p2[((long)(b * 256 + c0 + ty + r)) * SSk + s0 + tx];
    __syncthreads();
#pragma unroll
    for (int r = 0; r < 32; r += 8)
      p2t[((long)(b * SSk + s0 + ty + r)) * 256 + c0 + tx] = T[tx][ty + r];
  } else {
    // ---------------- weight f32->bf16
    int i = sub * 512 + threadIdx.x;
    if (i < 131072) wb1[i] = __float2bfloat16(w1[i]);
    else            wb2[i - 131072] = __float2bfloat16(w2[i - 131072]);
  }
}

// ---------------------------------------------------------------- gather + weighted interp -> xb[:,256:512]
__global__ void k_gather(const float* __restrict__ p2t, const int* __restrict__ idx3,
                         const float* __restrict__ w3, __hip_bfloat16* __restrict__ xb) {
  int b = blockIdx.y;
  int wid = threadIdx.x >> 6, lane = threadIdx.x & 63;
  int n = blockIdx.x * 4 + wid;                       // one wave per n
  long t = (long)b * NNq + n;
  long o = t * 3;
  int g0 = idx3[o], g1 = idx3[o + 1], g2 = idx3[o + 2];
  float w0 = w3[o], w1 = w3[o + 1], w2 = w3[o + 2];
  const float4* q0 = (const float4*)(p2t + ((long)(b * SSk + g0)) * 256);
  const float4* q1 = (const float4*)(p2t + ((long)(b * SSk + g1)) * 256);
  const float4* q2 = (const float4*)(p2t + ((long)(b * SSk + g2)) * 256);
  float4 a = q0[lane], c = q1[lane], d = q2[lane];
  float vx = w0 * a.x + w1 * c.x + w2 * d.x;
  float vy = w0 * a.y + w1 * c.y + w2 * d.y;
  float vz = w0 * a.z + w1 * c.z + w2 * d.z;
  float vw = w0 * a.w + w1 * c.w + w2 * d.w;
  ushort4 u;
  u.x = f2bf(vx); u.y = f2bf(vy); u.z = f2bf(vz); u.w = f2bf(vw);
  *(ushort4*)((unsigned short*)xb + t * CIN + 256 + lane * 4) = u;
}

// ---------------------------------------------------------------- GEMM (bf16 out) + fused BN partial stats
template <int K>
__global__ __launch_bounds__(256) void k_gemm(const __hip_bfloat16* __restrict__ X,
                                              const __hip_bfloat16* __restrict__ W,
                                              unsigned short* __restrict__ Yb,
                                              float* __restrict__ part) {
  constexpr int BK = 32;
  __shared__ __hip_bfloat16 xT[128 * BK];
  __shared__ __hip_bfloat16 wT[128 * BK];
  __shared__ float sb[4][4][16], qb[4][4][16];
  const int id = blockIdx.x;
  const int super = id >> 4, slot = id & 15;
  const int bx = super * 8 + (slot & 7);
  const int r0 = bx * 128;
  const int c0 = (slot >> 3) * 128;
  const int tid = threadIdx.x;
  const int wid = tid >> 6, lane = tid & 63;
  const int wr = wid >> 1, wc = wid & 1;
  f32x4 acc[4][4] = {};

  for (int kt = 0; kt < K; kt += BK) {
#pragma unroll
    for (int jj = 0; jj < 2; ++jj) {
      int j = wid * 2 + jj;
      int row = j * 16 + (lane >> 2);
      const __hip_bfloat16* g = X + ((long)(r0 + row)) * K + kt + (lane & 3) * 8;
      __builtin_amdgcn_global_load_lds((const __attribute__((address_space(1))) void*)(const void*)g,
                                       (__attribute__((address_space(3))) void*)(void*)(xT + j * 512),
                                       16, 0, 0);
    }
#pragma unroll
    for (int jj = 0; jj < 2; ++jj) {
      int j = wid * 2 + jj;
      int row = j * 16 + (lane >> 2);
      const __hip_bfloat16* g = W + ((long)(c0 + row)) * K + kt + (lane & 3) * 8;
      __builtin_amdgcn_global_load_lds((const __attribute__((address_space(1))) void*)(const void*)g,
                                       (__attribute__((address_space(3))) void*)(void*)(wT + j * 512),
                                       16, 0, 0);
    }
    __syncthreads();

    bf16x8 af[4], bfr[4];
#pragma unroll
    for (int m = 0; m < 4; ++m) {
      int row = wr * 64 + m * 16 + (lane & 15);
      af[m] = *(const bf16x8*)(xT + row * BK + (lane >> 4) * 8);
    }
#pragma unroll
    for (int nn = 0; nn < 4; ++nn) {
      int row = wc * 64 + nn * 16 + (lane & 15);
      bfr[nn] = *(const bf16x8*)(wT + row * BK + (lane >> 4) * 8);
    }
#pragma unroll
    for (int m = 0; m < 4; ++m)
#pragma unroll
      for (int nn = 0; nn < 4; ++nn)
        acc[m][nn] = __builtin_amdgcn_mfma_f32_16x16x32_bf16(af[m], bfr[nn], acc[m][nn], 0, 0, 0);
    __syncthreads();
  }

#pragma unroll
  for (int m = 0; m < 4; ++m)
#pragma unroll
    for (int nn = 0; nn < 4; ++nn)
#pragma unroll
      for (int reg = 0; reg < 4; ++reg) {
        int r = r0 + wr * 64 + m * 16 + (lane >> 4) * 4 + reg;
        int c = c0 + wc * 64 + nn * 16 + (lane & 15);
        Yb[(long)r * OC + c] = f2bf(acc[m][nn][reg]);
      }

#pragma unroll
  for (int nn = 0; nn < 4; ++nn) {
    float s = 0.f, q = 0.f;
#pragma unroll
    for (int m = 0; m < 4; ++m)
#pragma unroll
      for (int reg = 0; reg < 4; ++reg) {
        float v = acc[m][nn][reg];
        s += v; q += v * v;
      }
    s += __shfl_xor(s, 16); s += __shfl_xor(s, 32);
    q += __shfl_xor(q, 16); q += __shfl_xor(q, 32);
    if (lane < 16) { sb[wid][nn][lane] = s; qb[wid][nn][lane] = q; }
  }
  __syncthreads();
  if (tid < 128) {
    int col = tid & 15, nn = (tid >> 4) & 3, wcc = (tid >> 6) & 1;
    float s = sb[wcc][nn][col] + sb[2 + wcc][nn][col];
    float q = qb[wcc][nn][col] + qb[2 + wcc][nn][col];
    int ch = c0 + wcc * 64 + nn * 16 + col;
    part[(long)ch * NBX + bx] = s;
    part[(long)(256 + ch) * NBX + bx] = q;
  }
}

// ---------------------------------------------------------------- reduce partials, finalize BN scale/shift
__global__ void k_scalefix(const float* __restrict__ part, const float* __restrict__ g,
                           const float* __restrict__ be, float* __restrict__ st) {
  __shared__ float sred[8][33], qred[8][33];
  int ch_l = threadIdx.x >> 5, j = threadIdx.x & 31;
  int o = blockIdx.x * 8 + ch_l;
  const float4* ps = (const float4*)(part + (long)o * NBX + j * 16);
  const float4* pq = (const float4*)(part + (long)(256 + o) * NBX + j * 16);
  float s = 0.f, q = 0.f;
#pragma unroll
  for (int i = 0; i < 4; ++i) {
    float4 a = ps[i], bq = pq[i];
    s += (a.x + a.y) + (a.z + a.w);
    q += (bq.x + bq.y) + (bq.z + bq.w);
  }
  sred[ch_l][j] = s; qred[ch_l][j] = q;
  __syncthreads();
  if (threadIdx.x < 8) {
    int ch = threadIdx.x;
    float ss = 0.f, qq = 0.f;
#pragma unroll
    for (int i = 0; i < 32; ++i) { ss += sred[ch][i]; qq += qred[ch][i]; }
    int oo = blockIdx.x * 8 + ch;
    float mean = ss * (1.f / NR);
    float var = qq * (1.f / NR) - mean * mean;
    float sc = g[oo] * rsqrtf(var + 1e-5f);
    st[oo] = sc;
    st[OC + oo] = be[oo] - mean * sc;
  }
}

// ---------------------------------------------------------------- BN+ReLU: bf16 in -> bf16 out
__global__ void k_bnrelu_bf16(const unsigned short* __restrict__ Y, const float* __restrict__ st,
                              unsigned short* __restrict__ Yb) {
  long i8 = (long)blockIdx.x * 256 + threadIdx.x;
  ushort8 v = ((const ushort8*)Y)[i8];
  int c8 = (int)(i8 & 31);
  float4 sca = ((const float4*)st)[c8 * 2];
  float4 scb = ((const float4*)st)[c8 * 2 + 1];
  float4 sha = ((const float4*)(st + OC))[c8 * 2];
  float4 shb = ((const float4*)(st + OC))[c8 * 2 + 1];
  ushort8 u;
  u[0] = f2bf(fmaxf(fmaf(bf2f(v[0]), sca.x, sha.x), 0.f));
  u[1] = f2bf(fmaxf(fmaf(bf2f(v[1]), sca.y, sha.y), 0.f));
  u[2] = f2bf(fmaxf(fmaf(bf2f(v[2]), sca.z, sha.z), 0.f));
  u[3] = f2bf(fmaxf(fmaf(bf2f(v[3]), sca.w, sha.w), 0.f));
  u[4] = f2bf(fmaxf(fmaf(bf2f(v[4]), scb.x, shb.x), 0.f));
  u[5] = f2bf(fmaxf(fmaf(bf2f(v[5]), scb.y, shb.y), 0.f));
  u[6] = f2bf(fmaxf(fmaf(bf2f(v[6]), scb.z, shb.z), 0.f));
  u[7] = f2bf(fmaxf(fmaf(bf2f(v[7]), scb.w, shb.w), 0.f));
  ((ushort8*)Yb)[i8] = u;
}

// ---------------------------------------------------------------- BN+ReLU + transpose -> out [B][256][N] f32
__global__ void k_final(const unsigned short* __restrict__ Y, const float* __restrict__ st,
                        float* __restrict__ out) {
  __shared__ float tile[256][33];
  int b = blockIdx.z, o0 = blockIdx.y * 32, n0 = blockIdx.x * 256;
  int t = threadIdx.x;
  int cp = t & 15, tn = t >> 4;
  int c = cp * 2;
  float sc0 = st[o0 + c], sc1 = st[o0 + c + 1];
  float sh0 = st[OC + o0 + c], sh1 = st[OC + o0 + c + 1];
#pragma unroll
  for (int r = 0; r < 16; ++r) {
    int nl = r * 16 + tn;
    ushort2 v = *(const ushort2*)(Y + ((long)(b * NNq + n0 + nl)) * OC + o0 + c);
    tile[nl][c]     = fmaxf(fmaf(bf2f(v.x), sc0, sh0), 0.f);
    tile[nl][c + 1] = fmaxf(fmaf(bf2f(v.y), sc1, sh1), 0.f);
  }
  __syncthreads();
  int w = t >> 6, lane = t & 63;
#pragma unroll
  for (int rr = 0; rr < 8; ++rr) {
    int cl = w * 8 + rr;
    float4 v = make_float4(tile[lane * 4 + 0][cl], tile[lane * 4 + 1][cl],
                           tile[lane * 4 + 2][cl], tile[lane * 4 + 3][cl]);
    *(float4*)(out + ((long)(b * 256 + o0 + cl)) * NNq + n0 + lane * 4) = v;
  }
}

// ================================================================ launch
extern "C" void kernel_launch(void* const* d_in, const int* in_sizes, int n_in,
                              void* d_out, int out_size, void* d_ws, size_t ws_size,
                              hipStream_t stream) {
  const float* xyz1 = (const float*)d_in[0];
  const float* xyz2 = (const float*)d_in[1];
  const float* p1   = (const float*)d_in[2];
  const float* p2   = (const float*)d_in[3];
  const float* w1   = (const float*)d_in[4];
  // d_in[5] = b1 : cancels exactly under batch-norm mean subtraction
  const float* g1   = (const float*)d_in[6];
  const float* be1  = (const float*)d_in[7];
  const float* w2   = (const float*)d_in[8];
  // d_in[9] = b2 : cancels
  const float* g2   = (const float*)d_in[10];
  const float* be2  = (const float*)d_in[11];
  float* out = (float*)d_out;

  char* ws = (char*)d_ws;
  const size_t OFF_XB   = 0;
  const size_t OFF_Y1   = 67108864;
  const size_t OFF_P2T  = OFF_Y1;                  // p2t: first 16MB of Y1 region (dead before GEMM1)
  const size_t OFF_MISC = 134217728;
  const size_t OFF_IDX  = OFF_MISC + 262144;       // 768KB
  const size_t OFF_W3   = OFF_MISC + 1048576;      // 768KB
  const size_t OFF_WB1  = OFF_MISC + 1835008;
  const size_t OFF_WB2  = OFF_MISC + 2097152;
  const size_t OFF_ST1  = OFF_MISC + 2228224;
  const size_t OFF_ST2  = OFF_MISC + 2230272;
  const size_t OFF_PART = OFF_IDX;                 // 1MB alias (idx3/w3 dead after k_gather)

  __hip_bfloat16* xb   = (__hip_bfloat16*)(ws + OFF_XB);
  unsigned short* y1   = (unsigned short*)(ws + OFF_Y1);
  unsigned short* y2   = (unsigned short*)(ws + OFF_Y1);
  float* p2t           = (float*)(ws + OFF_P2T);
  int*   idx3          = (int*)(ws + OFF_IDX);
  float* w3            = (float*)(ws + OFF_W3);
  __hip_bfloat16* wb1  = (__hip_bfloat16*)(ws + OFF_WB1);
  __hip_bfloat16* wb2  = (__hip_bfloat16*)(ws + OFF_WB2);
  unsigned short* y1b  = (unsigned short*)(ws + OFF_XB);
  float* st1           = (float*)(ws + OFF_ST1);
  float* st2           = (float*)(ws + OFF_ST2);
  float* part          = (float*)(ws + OFF_PART);

  // fat front: 512 knn (spread at id%8==0 in [0,4096)) + 10624 memory blocks
  k_front<<<11264, 512, 0, stream>>>(xyz1, xyz2, p1, p2, w1, w2, idx3, w3, xb, p2t, wb1, wb2);
  k_gather<<<dim3(NNq / 4, BB), 256, 0, stream>>>(p2t, idx3, w3, xb);

  k_gemm<512><<<2 * NBX, 256, 0, stream>>>(xb, wb1, y1, part);
  k_scalefix<<<32, 256, 0, stream>>>(part, g1, be1, st1);
  k_bnrelu_bf16<<<(int)((long)NR * 256 / 8 / 256), 256, 0, stream>>>(y1, st1, y1b);

  k_gemm<256><<<2 * NBX, 256, 0, stream>>>((const __hip_bfloat16*)y1b, wb2, y2, part);
  k_scalefix<<<32, 256, 0, stream>>>(part, g2, be2, st2);
  k_final<<<dim3(NNq / 256, 256 / 32, BB), 256, 0, stream>>>(y2, st2, out);

  (void)in_sizes; (void)n_in; (void)out_size; (void)ws_size;
}

// Round 13
// 198.426 us; speedup vs baseline: 2.6288x; 2.6288x over previous
//
#include <hip/hip_runtime.h>
#include <hip/hip_bf16.h>
#include <float.h>

#define BB 8
#define NNq 8192
#define SSk 2048
#define CIN 512
#define OC 256
#define NR (BB * NNq)   // 65536 total rows (b*N+n)
#define NBX 512         // GEMM row-blocks = NR/128
#define KNN_HALF 1024   // candidates per knn block (split over blockIdx.z)

typedef __attribute__((ext_vector_type(8))) short bf16x8;
typedef __attribute__((ext_vector_type(8))) unsigned short ushort8;
typedef __attribute__((ext_vector_type(4))) float f32x4;
typedef __attribute__((ext_vector_type(2))) float f32x2;

__device__ __forceinline__ unsigned short f2bf(float f) {
  union { __hip_bfloat16 h; unsigned short u; } v;
  v.h = __float2bfloat16(f);
  return v.u;
}
__device__ __forceinline__ float bf2f(unsigned short u) {
  union { unsigned int i; float f; } x; x.i = ((unsigned int)u) << 16; return x.f;
}

// packed distance for 2 queries vs 1 candidate; candidate stored as (-2qx,-2qy,-2qz,qq).
// bit-exact np order: t=((x*qx'+y*qy')+z*qz'); d=((t)+pp)+qq
__device__ __forceinline__ f32x2 pkdist(f32x2 xp, f32x2 yp, f32x2 zp, f32x2 pp2,
                                        f32x2 cxy, f32x2 czw) {
  f32x2 t, m;
  asm("v_pk_mul_f32 %0, %2, %6 op_sel:[0,0] op_sel_hi:[1,0]\n\t"
      "v_pk_mul_f32 %1, %3, %6 op_sel:[0,1] op_sel_hi:[1,1]\n\t"
      "v_pk_add_f32 %0, %0, %1\n\t"
      "v_pk_mul_f32 %1, %4, %7 op_sel:[0,0] op_sel_hi:[1,0]\n\t"
      "v_pk_add_f32 %0, %0, %1\n\t"
      "v_pk_add_f32 %0, %0, %5\n\t"
      "v_pk_add_f32 %0, %0, %7 op_sel:[0,1] op_sel_hi:[1,1]"
      : "=&v"(t), "=&v"(m)
      : "v"(xp), "v"(yp), "v"(zp), "v"(pp2), "v"(cxy), "v"(czw));
  return t;
}

// fused dual sorted-insert, hazard-free: 6 sgpr-pair masks written up-front,
// every mask read >=5 instrs after its write (no s_nop wait-states).
// semantics identical to the ternary/med3 chain; strict < keeps earlier index on ties.
__device__ __forceinline__ void insert3x2(float dA, float dB, int ix,
    float& e0A, float& e1A, float& e2A, int& i0A, int& i1A, int& i2A,
    float& e0B, float& e1B, float& e2B, int& i0B, int& i1B, int& i2B) {
  int tA, tB;
  unsigned long long sA2, sB2, sA1, sB1, sA0, sB0;
  asm("v_cmp_lt_f32 %[sA2], %[dA], %[e2A]\n\t"
      "v_cmp_lt_f32 %[sB2], %[dB], %[e2B]\n\t"
      "v_cmp_lt_f32 %[sA1], %[dA], %[e1A]\n\t"
      "v_cmp_lt_f32 %[sB1], %[dB], %[e1B]\n\t"
      "v_cmp_lt_f32 %[sA0], %[dA], %[e0A]\n\t"
      "v_cmp_lt_f32 %[sB0], %[dB], %[e0B]\n\t"
      "v_cndmask_b32 %[tA], %[i2A], %[ix], %[sA2]\n\t"
      "v_cndmask_b32 %[tB], %[i2B], %[ix], %[sB2]\n\t"
      "v_cndmask_b32 %[i2A], %[tA], %[i1A], %[sA1]\n\t"
      "v_cndmask_b32 %[i2B], %[tB], %[i1B], %[sB1]\n\t"
      "v_cndmask_b32 %[tA], %[i1A], %[ix], %[sA1]\n\t"
      "v_cndmask_b32 %[tB], %[i1B], %[ix], %[sB1]\n\t"
      "v_cndmask_b32 %[i1A], %[tA], %[i0A], %[sA0]\n\t"
      "v_cndmask_b32 %[i1B], %[tB], %[i0B], %[sB0]\n\t"
      "v_cndmask_b32 %[i0A], %[i0A], %[ix], %[sA0]\n\t"
      "v_cndmask_b32 %[i0B], %[i0B], %[ix], %[sB0]\n\t"
      "v_med3_f32 %[e2A], %[dA], %[e1A], %[e2A]\n\t"
      "v_med3_f32 %[e2B], %[dB], %[e1B], %[e2B]\n\t"
      "v_med3_f32 %[e1A], %[dA], %[e0A], %[e1A]\n\t"
      "v_med3_f32 %[e1B], %[dB], %[e0B], %[e1B]\n\t"
      "v_min_f32 %[e0A], %[e0A], %[dA]\n\t"
      "v_min_f32 %[e0B], %[e0B], %[dB]"
      : [e0A]"+v"(e0A), [e1A]"+v"(e1A), [e2A]"+v"(e2A),
        [i0A]"+v"(i0A), [i1A]"+v"(i1A), [i2A]"+v"(i2A),
        [e0B]"+v"(e0B), [e1B]"+v"(e1B), [e2B]"+v"(e2B),
        [i0B]"+v"(i0B), [i1B]"+v"(i1B), [i2B]"+v"(i2B),
        [tA]"=&v"(tA), [tB]"=&v"(tB),
        [sA2]"=&s"(sA2), [sB2]"=&s"(sB2), [sA1]"=&s"(sA1),
        [sB1]"=&s"(sB1), [sA0]"=&s"(sA0), [sB0]"=&s"(sB0)
      : [dA]"v"(dA), [dB]"v"(dB), [ix]"v"(ix));
}

// ---------------------------------------------------------------- fused prep: weight cvt + hq build
// hq = (-2x, -2y, -2z, qq) ; qq np-exact from original coords
__global__ void k_misc(const float* __restrict__ w1, const float* __restrict__ w2,
                       const float* __restrict__ xyz2,
                       __hip_bfloat16* __restrict__ wb1, __hip_bfloat16* __restrict__ wb2,
                       float4* __restrict__ hq) {
  int i = blockIdx.x * 256 + threadIdx.x;
  if (i < 131072) {
    wb1[i] = __float2bfloat16(w1[i]);
  } else if (i < 196608) {
    int j = i - 131072;
    wb2[j] = __float2bfloat16(w2[j]);
  } else {
    int p = i - 196608;   // < 16384
    float x = xyz2[p * 3 + 0], y = xyz2[p * 3 + 1], z = xyz2[p * 3 + 2];
    float qq = __fadd_rn(__fadd_rn(__fmul_rn(x, x), __fmul_rn(y, y)), __fmul_rn(z, z));
    hq[p] = make_float4(-2.f * x, -2.f * y, -2.f * z, qq);
  }
}

// ---------------------------------------------------------------- knn scan: 128 q/block (2/lane), half the
// candidates per block (blockIdx.z), 8 waves x 128-chunk. Writes per-half top-3 partials.
__global__ __launch_bounds__(512) void k_knn(const float* __restrict__ xyz1,
                                             const float4* __restrict__ hq,
                                             float* __restrict__ pe, int* __restrict__ pi) {
  __shared__ float4 lsh[1536];         // 24KB: [0,1024) candidates; merge overlay uses 24KB
  float* meP = (float*)lsh;            // [8][3][128] floats (12KB)
  int*   miP = (int*)lsh + 3072;       // [8][3][128] ints   (12KB)
  int b = blockIdx.y, half = blockIdx.z;
  int t = threadIdx.x;
  int lane = t & 63, w = t >> 6;       // 8 waves

  const float4* __restrict__ hsrc = hq + (long)b * SSk + half * KNN_HALF;
  lsh[t] = hsrc[t];
  lsh[t + 512] = hsrc[t + 512];

  // two queries per lane: nA = blk*128+lane, nB = +64
  long baseA = (long)b * NNq + blockIdx.x * 128 + lane;
  long baseB = baseA + 64;
  float xa = xyz1[baseA * 3 + 0], ya = xyz1[baseA * 3 + 1], za = xyz1[baseA * 3 + 2];
  float xb_ = xyz1[baseB * 3 + 0], yb_ = xyz1[baseB * 3 + 1], zb_ = xyz1[baseB * 3 + 2];
  float ppa = __fadd_rn(__fadd_rn(__fmul_rn(xa, xa), __fmul_rn(ya, ya)), __fmul_rn(za, za));
  float ppb = __fadd_rn(__fadd_rn(__fmul_rn(xb_, xb_), __fmul_rn(yb_, yb_)), __fmul_rn(zb_, zb_));
  f32x2 xp = {xa, xb_}, yp = {ya, yb_}, zp = {za, zb_}, pp2 = {ppa, ppb};
  __syncthreads();

  float e0a = FLT_MAX, e1a = FLT_MAX, e2a = FLT_MAX;
  float e0b = FLT_MAX, e1b = FLT_MAX, e2b = FLT_MAX;
  int i0a = 0, i1a = 0, i2a = 0, i0b = 0, i1b = 0, i2b = 0;
  const f32x4* __restrict__ qp = (const f32x4*)(lsh + w * 128);
#pragma unroll 8
  for (int ii = 0; ii < 128; ++ii) {
    f32x4 c = qp[ii];
    f32x2 d2 = pkdist(xp, yp, zp, pp2, c.xy, c.zw);
    insert3x2(d2.x, d2.y, ii,
              e0a, e1a, e2a, i0a, i1a, i2a,
              e0b, e1b, e2b, i0b, i1b, i2b);
  }
  __syncthreads();   // all waves done reading candidates; safe to overlay
  int s0 = half * KNN_HALF + w * 128;
  meP[(w * 3 + 0) * 128 + lane] = e0a; meP[(w * 3 + 1) * 128 + lane] = e1a; meP[(w * 3 + 2) * 128 + lane] = e2a;
  meP[(w * 3 + 0) * 128 + 64 + lane] = e0b; meP[(w * 3 + 1) * 128 + 64 + lane] = e1b; meP[(w * 3 + 2) * 128 + 64 + lane] = e2b;
  miP[(w * 3 + 0) * 128 + lane] = i0a + s0; miP[(w * 3 + 1) * 128 + lane] = i1a + s0; miP[(w * 3 + 2) * 128 + lane] = i2a + s0;
  miP[(w * 3 + 0) * 128 + 64 + lane] = i0b + s0; miP[(w * 3 + 1) * 128 + 64 + lane] = i1b + s0; miP[(w * 3 + 2) * 128 + 64 + lane] = i2b + s0;
  __syncthreads();

  if (t < 128) {
    // merge 8 chunk-triples in ascending chunk order (stable ties)
    float e0 = meP[0 * 128 + t], e1 = meP[1 * 128 + t], e2 = meP[2 * 128 + t];
    int   g0 = miP[0 * 128 + t], g1 = miP[1 * 128 + t], g2 = miP[2 * 128 + t];
    for (int ww = 1; ww < 8; ++ww) {
#pragma unroll
      for (int k = 0; k < 3; ++k) {
        float d = meP[(ww * 3 + k) * 128 + t]; int s = miP[(ww * 3 + k) * 128 + t];
        if (d < e2) {
          if (d < e1) {
            e2 = e1; g2 = g1;
            if (d < e0) { e1 = e0; g1 = g0; e0 = d; g0 = s; }
            else        { e1 = d; g1 = s; }
          } else { e2 = d; g2 = s; }
        }
      }
    }
    long base = (long)b * NNq + blockIdx.x * 128 + t;
    long o = ((long)half * NR + base) * 3;
    pe[o + 0] = e0; pe[o + 1] = e1; pe[o + 2] = e2;
    pi[o + 0] = g0; pi[o + 1] = g1; pi[o + 2] = g2;
  }
}

// ---------------------------------------------------------------- transpose points1 -> xb[:,0:256] (bf16)
__global__ void k_tr_p1(const float* __restrict__ p1, __hip_bfloat16* __restrict__ xb) {
  __shared__ float tile[32][33];
  int b = blockIdx.z, c0 = blockIdx.y * 32, n0 = blockIdx.x * 32;
  int tx = threadIdx.x & 31, ty = threadIdx.x >> 5;   // 32x8
#pragma unroll
  for (int r = 0; r < 32; r += 8)
    tile[ty + r][tx] = p1[((long)(b * 256 + c0 + ty + r)) * NNq + n0 + tx];
  __syncthreads();
#pragma unroll
  for (int r = 0; r < 32; r += 8)
    xb[((long)(b * NNq + n0 + ty + r)) * CIN + c0 + tx] = __float2bfloat16(tile[tx][ty + r]);
}

// ---------------------------------------------------------------- transpose points2 -> p2t [B][S][256] f32
__global__ void k_tr_p2(const float* __restrict__ p2, float* __restrict__ p2t) {
  __shared__ float tile[32][33];
  int b = blockIdx.z, c0 = blockIdx.y * 32, s0 = blockIdx.x * 32;
  int tx = threadIdx.x & 31, ty = threadIdx.x >> 5;
#pragma unroll
  for (int r = 0; r < 32; r += 8)
    tile[ty + r][tx] = p2[((long)(b * 256 + c0 + ty + r)) * SSk + s0 + tx];
  __syncthreads();
#pragma unroll
  for (int r = 0; r < 32; r += 8)
    p2t[((long)(b * SSk + s0 + ty + r)) * 256 + c0 + tx] = tile[tx][ty + r];
}

// ---------------------------------------------------------------- fused half-merge + gather + interp
__global__ void k_gather(const float* __restrict__ p2t, const float* __restrict__ pe,
                         const int* __restrict__ pi, __hip_bfloat16* __restrict__ xb) {
  int b = blockIdx.y;
  int wid = threadIdx.x >> 6, lane = threadIdx.x & 63;
  int n = blockIdx.x * 4 + wid;                       // one wave per n
  long t = (long)b * NNq + n;
  float e0 = pe[t * 3 + 0], e1 = pe[t * 3 + 1], e2 = pe[t * 3 + 2];
  int   g0 = pi[t * 3 + 0], g1 = pi[t * 3 + 1], g2 = pi[t * 3 + 2];
  long o1 = ((long)NR + t) * 3;
#pragma unroll
  for (int k = 0; k < 3; ++k) {
    float d = pe[o1 + k]; int s = pi[o1 + k];
    if (d < e2) {
      if (d < e1) {
        e2 = e1; g2 = g1;
        if (d < e0) { e1 = e0; g1 = g0; e0 = d; g0 = s; }
        else        { e1 = d; g1 = s; }
      } else { e2 = d; g2 = s; }
    }
  }
  float r0 = 1.f / (e0 + 1e-8f), r1 = 1.f / (e1 + 1e-8f), r2 = 1.f / (e2 + 1e-8f);
  float rs = r0 + r1 + r2;
  float w0 = r0 / rs, w1 = r1 / rs, w2 = r2 / rs;

  const float4* q0 = (const float4*)(p2t + ((long)(b * SSk + g0)) * 256);
  const float4* q1 = (const float4*)(p2t + ((long)(b * SSk + g1)) * 256);
  const float4* q2 = (const float4*)(p2t + ((long)(b * SSk + g2)) * 256);
  float4 a = q0[lane], c = q1[lane], d = q2[lane];
  float vx = w0 * a.x + w1 * c.x + w2 * d.x;
  float vy = w0 * a.y + w1 * c.y + w2 * d.y;
  float vz = w0 * a.z + w1 * c.z + w2 * d.z;
  float vw = w0 * a.w + w1 * c.w + w2 * d.w;
  ushort4 u;
  u.x = f2bf(vx); u.y = f2bf(vy); u.z = f2bf(vz); u.w = f2bf(vw);
  *(ushort4*)((unsigned short*)xb + t * CIN + 256 + lane * 4) = u;
}

// ---------------------------------------------------------------- GEMM (bf16 out) + fused BN partial stats
template <int K>
__global__ __launch_bounds__(256) void k_gemm(const __hip_bfloat16* __restrict__ X,
                                              const __hip_bfloat16* __restrict__ W,
                                              unsigned short* __restrict__ Yb,
                                              float* __restrict__ part) {
  constexpr int BK = 32;
  __shared__ __hip_bfloat16 xT[128 * BK];
  __shared__ __hip_bfloat16 wT[128 * BK];
  __shared__ float sb[4][4][16], qb[4][4][16];
  const int id = blockIdx.x;
  const int super = id >> 4, slot = id & 15;
  const int bx = super * 8 + (slot & 7);
  const int r0 = bx * 128;
  const int c0 = (slot >> 3) * 128;
  const int tid = threadIdx.x;
  const int wid = tid >> 6, lane = tid & 63;
  const int wr = wid >> 1, wc = wid & 1;
  f32x4 acc[4][4] = {};

  for (int kt = 0; kt < K; kt += BK) {
#pragma unroll
    for (int jj = 0; jj < 2; ++jj) {
      int j = wid * 2 + jj;
      int row = j * 16 + (lane >> 2);
      const __hip_bfloat16* g = X + ((long)(r0 + row)) * K + kt + (lane & 3) * 8;
      __builtin_amdgcn_global_load_lds((const __attribute__((address_space(1))) void*)(const void*)g,
                                       (__attribute__((address_space(3))) void*)(void*)(xT + j * 512),
                                       16, 0, 0);
    }
#pragma unroll
    for (int jj = 0; jj < 2; ++jj) {
      int j = wid * 2 + jj;
      int row = j * 16 + (lane >> 2);
      const __hip_bfloat16* g = W + ((long)(c0 + row)) * K + kt + (lane & 3) * 8;
      __builtin_amdgcn_global_load_lds((const __attribute__((address_space(1))) void*)(const void*)g,
                                       (__attribute__((address_space(3))) void*)(void*)(wT + j * 512),
                                       16, 0, 0);
    }
    __syncthreads();

    bf16x8 af[4], bfr[4];
#pragma unroll
    for (int m = 0; m < 4; ++m) {
      int row = wr * 64 + m * 16 + (lane & 15);
      af[m] = *(const bf16x8*)(xT + row * BK + (lane >> 4) * 8);
    }
#pragma unroll
    for (int nn = 0; nn < 4; ++nn) {
      int row = wc * 64 + nn * 16 + (lane & 15);
      bfr[nn] = *(const bf16x8*)(wT + row * BK + (lane >> 4) * 8);
    }
#pragma unroll
    for (int m = 0; m < 4; ++m)
#pragma unroll
      for (int nn = 0; nn < 4; ++nn)
        acc[m][nn] = __builtin_amdgcn_mfma_f32_16x16x32_bf16(af[m], bfr[nn], acc[m][nn], 0, 0, 0);
    __syncthreads();
  }

#pragma unroll
  for (int m = 0; m < 4; ++m)
#pragma unroll
    for (int nn = 0; nn < 4; ++nn)
#pragma unroll
      for (int reg = 0; reg < 4; ++reg) {
        int r = r0 + wr * 64 + m * 16 + (lane >> 4) * 4 + reg;
        int c = c0 + wc * 64 + nn * 16 + (lane & 15);
        Yb[(long)r * OC + c] = f2bf(acc[m][nn][reg]);
      }

#pragma unroll
  for (int nn = 0; nn < 4; ++nn) {
    float s = 0.f, q = 0.f;
#pragma unroll
    for (int m = 0; m < 4; ++m)
#pragma unroll
      for (int reg = 0; reg < 4; ++reg) {
        float v = acc[m][nn][reg];
        s += v; q += v * v;
      }
    s += __shfl_xor(s, 16); s += __shfl_xor(s, 32);
    q += __shfl_xor(q, 16); q += __shfl_xor(q, 32);
    if (lane < 16) { sb[wid][nn][lane] = s; qb[wid][nn][lane] = q; }
  }
  __syncthreads();
  if (tid < 128) {
    int col = tid & 15, nn = (tid >> 4) & 3, wcc = (tid >> 6) & 1;
    float s = sb[wcc][nn][col] + sb[2 + wcc][nn][col];
    float q = qb[wcc][nn][col] + qb[2 + wcc][nn][col];
    int ch = c0 + wcc * 64 + nn * 16 + col;
    part[(long)ch * NBX + bx] = s;
    part[(long)(256 + ch) * NBX + bx] = q;
  }
}

// ---------------------------------------------------------------- reduce partials, finalize BN scale/shift
__global__ void k_scalefix(const float* __restrict__ part, const float* __restrict__ g,
                           const float* __restrict__ be, float* __restrict__ st) {
  __shared__ float sred[8][33], qred[8][33];
  int ch_l = threadIdx.x >> 5, j = threadIdx.x & 31;
  int o = blockIdx.x * 8 + ch_l;
  const float4* ps = (const float4*)(part + (long)o * NBX + j * 16);
  const float4* pq = (const float4*)(part + (long)(256 + o) * NBX + j * 16);
  float s = 0.f, q = 0.f;
#pragma unroll
  for (int i = 0; i < 4; ++i) {
    float4 a = ps[i], bq = pq[i];
    s += (a.x + a.y) + (a.z + a.w);
    q += (bq.x + bq.y) + (bq.z + bq.w);
  }
  sred[ch_l][j] = s; qred[ch_l][j] = q;
  __syncthreads();
  if (threadIdx.x < 8) {
    int ch = threadIdx.x;
    float ss = 0.f, qq = 0.f;
#pragma unroll
    for (int i = 0; i < 32; ++i) { ss += sred[ch][i]; qq += qred[ch][i]; }
    int oo = blockIdx.x * 8 + ch;
    float mean = ss * (1.f / NR);
    float var = qq * (1.f / NR) - mean * mean;
    float sc = g[oo] * rsqrtf(var + 1e-5f);
    st[oo] = sc;
    st[OC + oo] = be[oo] - mean * sc;
  }
}

// ---------------------------------------------------------------- BN+ReLU: bf16 in -> bf16 out
__global__ void k_bnrelu_bf16(const unsigned short* __restrict__ Y, const float* __restrict__ st,
                              unsigned short* __restrict__ Yb) {
  long i8 = (long)blockIdx.x * 256 + threadIdx.x;
  ushort8 v = ((const ushort8*)Y)[i8];
  int c8 = (int)(i8 & 31);
  float4 sca = ((const float4*)st)[c8 * 2];
  float4 scb = ((const float4*)st)[c8 * 2 + 1];
  float4 sha = ((const float4*)(st + OC))[c8 * 2];
  float4 shb = ((const float4*)(st + OC))[c8 * 2 + 1];
  ushort8 u;
  u[0] = f2bf(fmaxf(fmaf(bf2f(v[0]), sca.x, sha.x), 0.f));
  u[1] = f2bf(fmaxf(fmaf(bf2f(v[1]), sca.y, sha.y), 0.f));
  u[2] = f2bf(fmaxf(fmaf(bf2f(v[2]), sca.z, sha.z), 0.f));
  u[3] = f2bf(fmaxf(fmaf(bf2f(v[3]), sca.w, sha.w), 0.f));
  u[4] = f2bf(fmaxf(fmaf(bf2f(v[4]), scb.x, shb.x), 0.f));
  u[5] = f2bf(fmaxf(fmaf(bf2f(v[5]), scb.y, shb.y), 0.f));
  u[6] = f2bf(fmaxf(fmaf(bf2f(v[6]), scb.z, shb.z), 0.f));
  u[7] = f2bf(fmaxf(fmaf(bf2f(v[7]), scb.w, shb.w), 0.f));
  ((ushort8*)Yb)[i8] = u;
}

// ---------------------------------------------------------------- BN+ReLU + transpose -> out [B][256][N] f32
__global__ void k_final(const unsigned short* __restrict__ Y, const float* __restrict__ st,
                        float* __restrict__ out) {
  __shared__ float tile[256][33];
  int b = blockIdx.z, o0 = blockIdx.y * 32, n0 = blockIdx.x * 256;
  int t = threadIdx.x;
  int cp = t & 15, tn = t >> 4;
  int c = cp * 2;
  float sc0 = st[o0 + c], sc1 = st[o0 + c + 1];
  float sh0 = st[OC + o0 + c], sh1 = st[OC + o0 + c + 1];
#pragma unroll
  for (int r = 0; r < 16; ++r) {
    int nl = r * 16 + tn;
    ushort2 v = *(const ushort2*)(Y + ((long)(b * NNq + n0 + nl)) * OC + o0 + c);
    tile[nl][c]     = fmaxf(fmaf(bf2f(v.x), sc0, sh0), 0.f);
    tile[nl][c + 1] = fmaxf(fmaf(bf2f(v.y), sc1, sh1), 0.f);
  }
  __syncthreads();
  int w = t >> 6, lane = t & 63;
#pragma unroll
  for (int rr = 0; rr < 8; ++rr) {
    int cl = w * 8 + rr;
    float4 v = make_float4(tile[lane * 4 + 0][cl], tile[lane * 4 + 1][cl],
                           tile[lane * 4 + 2][cl], tile[lane * 4 + 3][cl]);
    *(float4*)(out + ((long)(b * 256 + o0 + cl)) * NNq + n0 + lane * 4) = v;
  }
}

// ================================================================ launch
extern "C" void kernel_launch(void* const* d_in, const int* in_sizes, int n_in,
                              void* d_out, int out_size, void* d_ws, size_t ws_size,
                              hipStream_t stream) {
  const float* xyz1 = (const float*)d_in[0];
  const float* xyz2 = (const float*)d_in[1];
  const float* p1   = (const float*)d_in[2];
  const float* p2   = (const float*)d_in[3];
  const float* w1   = (const float*)d_in[4];
  // d_in[5] = b1 : cancels exactly under batch-norm mean subtraction
  const float* g1   = (const float*)d_in[6];
  const float* be1  = (const float*)d_in[7];
  const float* w2   = (const float*)d_in[8];
  // d_in[9] = b2 : cancels
  const float* g2   = (const float*)d_in[10];
  const float* be2  = (const float*)d_in[11];
  float* out = (float*)d_out;

  char* ws = (char*)d_ws;
  const size_t OFF_XB   = 0;
  const size_t OFF_Y1   = 67108864;
  const size_t OFF_P2T  = OFF_Y1;                  // p2t: first 16MB of Y1 region (dead before GEMM1)
  const size_t OFF_PE   = OFF_Y1 + 16777216;       // knn partials: 3MB (dead before GEMM1)
  const size_t OFF_PI   = OFF_PE + 1572864;
  const size_t OFF_MISC = 134217728;
  const size_t OFF_HQ   = OFF_MISC + 0;
  const size_t OFF_WB1  = OFF_MISC + 1835008;
  const size_t OFF_WB2  = OFF_MISC + 2097152;
  const size_t OFF_ST1  = OFF_MISC + 2228224;
  const size_t OFF_ST2  = OFF_MISC + 2230272;
  const size_t OFF_PART = OFF_MISC + 262144;       // 1MB

  __hip_bfloat16* xb   = (__hip_bfloat16*)(ws + OFF_XB);
  unsigned short* y1   = (unsigned short*)(ws + OFF_Y1);
  unsigned short* y2   = (unsigned short*)(ws + OFF_Y1);
  float* p2t           = (float*)(ws + OFF_P2T);
  float* pe            = (float*)(ws + OFF_PE);
  int*   pi            = (int*)(ws + OFF_PI);
  float4* hq           = (float4*)(ws + OFF_HQ);
  __hip_bfloat16* wb1  = (__hip_bfloat16*)(ws + OFF_WB1);
  __hip_bfloat16* wb2  = (__hip_bfloat16*)(ws + OFF_WB2);
  unsigned short* y1b  = (unsigned short*)(ws + OFF_XB);
  float* st1           = (float*)(ws + OFF_ST1);
  float* st2           = (float*)(ws + OFF_ST2);
  float* part          = (float*)(ws + OFF_PART);

  k_misc<<<832, 256, 0, stream>>>(w1, w2, xyz2, wb1, wb2, hq);
  k_knn<<<dim3(NNq / 128, BB, 2), 512, 0, stream>>>(xyz1, hq, pe, pi);
  k_tr_p1<<<dim3(NNq / 32, 256 / 32, BB), 256, 0, stream>>>(p1, xb);
  k_tr_p2<<<dim3(SSk / 32, 256 / 32, BB), 256, 0, stream>>>(p2, p2t);
  k_gather<<<dim3(NNq / 4, BB), 256, 0, stream>>>(p2t, pe, pi, xb);

  k_gemm<512><<<2 * NBX, 256, 0, stream>>>(xb, wb1, y1, part);
  k_scalefix<<<32, 256, 0, stream>>>(part, g1, be1, st1);
  k_bnrelu_bf16<<<(int)((long)NR * 256 / 8 / 256), 256, 0, stream>>>(y1, st1, y1b);

  k_gemm<256><<<2 * NBX, 256, 0, stream>>>((const __hip_bfloat16*)y1b, wb2, y2, part);
  k_scalefix<<<32, 256, 0, stream>>>(part, g2, be2, st2);
  k_final<<<dim3(NNq / 256, 256 / 32, BB), 256, 0, stream>>>(y2, st2, out);

  (void)in_sizes; (void)n_in; (void)out_size; (void)ws_size;
}